// Round 16
// baseline (181.249 us; speedup 1.0000x reference)
//
#include <hip/hip_runtime.h>

// Problem constants (fixed by the reference)
#define B_  2
#define S_  2048
#define D_  1024
#define H_  16
#define HD_ 64
#define M_  (B_*S_)   // 4096 rows in all GEMMs

typedef __attribute__((ext_vector_type(8))) short s16x8;    // 8 bf16 MFMA operand
typedef __attribute__((ext_vector_type(4))) float f32x4;
typedef __attribute__((ext_vector_type(16))) float f32x16;  // 32x32 MFMA accumulator

__device__ __forceinline__ unsigned short f2bf(float f) {
  unsigned int u = __builtin_bit_cast(unsigned int, f);
  u += 0x7fffu + ((u >> 16) & 1u);          // round-to-nearest-even
  return (unsigned short)(u >> 16);
}
__device__ __forceinline__ float bf2f(unsigned short h) {
  unsigned int u = ((unsigned int)h) << 16;
  return __builtin_bit_cast(float, u);
}

// async global->LDS, 16B per lane; LDS dest is wave-uniform base (HW adds lane*16)
__device__ __forceinline__ void gload_lds16(const unsigned short* g, unsigned short* l) {
  __builtin_amdgcn_global_load_lds((const __attribute__((address_space(1))) void*)g,
                                   (__attribute__((address_space(3))) void*)l, 16, 0, 0);
}

// ---------------- elementwise f32 -> bf16 (x4 vectorized) ----------------
__global__ void cvt_kernel(const float* __restrict__ in, unsigned short* __restrict__ out, int n4) {
  int i = blockIdx.x * blockDim.x + threadIdx.x;
  if (i >= n4) return;
  float4 v = reinterpret_cast<const float4*>(in)[i];
  ushort4 o;
  o.x = f2bf(v.x); o.y = f2bf(v.y); o.z = f2bf(v.z); o.w = f2bf(v.w);
  reinterpret_cast<ushort4*>(out)[i] = o;
}

// ---------------- 3x 1024x1024 transpose+convert in one dispatch ----------------
__global__ void transpose_cvt3(const float* __restrict__ W0, const float* __restrict__ W1,
                               const float* __restrict__ W2, unsigned short* __restrict__ dstBase) {
  __shared__ float tile[32][33];
  const float* in = blockIdx.z == 0 ? W0 : (blockIdx.z == 1 ? W1 : W2);
  unsigned short* out = dstBase + (size_t)blockIdx.z * 1024 * 1024;
  const int bx = blockIdx.x, by = blockIdx.y, tx = threadIdx.x;
  const int x = bx * 32 + tx;
  for (int j = threadIdx.y; j < 32; j += 8)
    tile[j][tx] = in[(by * 32 + j) * 1024 + x];
  __syncthreads();
  const int xo = by * 32 + tx;
  for (int j = threadIdx.y; j < 32; j += 8)
    out[(bx * 32 + j) * 1024 + xo] = f2bf(tile[tx][j]);
}

// ---------------- bf16 MFMA GEMM (global_load_lds staging + XOR-swizzled LDS) ----------------
// (round-8 verified: swizzle killed the 16-way ds_read conflict)
#define BM 128
#define BN 128
#define BK 64

__global__ __launch_bounds__(256, 4) void gemm_bt(
    const unsigned short* __restrict__ A,
    const unsigned short* __restrict__ Bt,
    void* __restrict__ out0, void* __restrict__ out1, void* __restrict__ out2,
    const float* __restrict__ bias,
    const int mode, const float qscale)
{
  __shared__ unsigned short As[BM * BK];
  __shared__ unsigned short Bs[BN * BK];

  const int t    = threadIdx.x;
  const int lane = t & 63;
  const int wid  = t >> 6;
  const int l15  = lane & 15;
  const int g    = lane >> 4;
  const int wm   = wid >> 1;   // 2x2 waves, each 64x64
  const int wn   = wid & 1;

  const int n0 = blockIdx.x * BN;
  const int m0 = blockIdx.y * BM;

  const int lrow = lane >> 3;                         // row within 8-row chunk
  const int lcol = ((lane & 7) ^ lrow) * 8;           // pre-swizzled source granule
  const int rsw  = l15 & 7;                           // read-side XOR key (row&7)

  f32x4 acc[4][4];
#pragma unroll
  for (int i = 0; i < 4; ++i)
#pragma unroll
    for (int j = 0; j < 4; ++j)
      acc[i][j] = (f32x4){0.f, 0.f, 0.f, 0.f};

  for (int kt = 0; kt < 1024 / BK; ++kt) {
    const int k0 = kt * BK;
#pragma unroll
    for (int p = 0; p < 4; ++p) {
      const int c = p * 4 + wid;            // wave-uniform chunk id (8 rows = 1KB)
      const int row = c * 8 + lrow;
      gload_lds16(&A[(size_t)(m0 + row) * 1024 + k0 + lcol], &As[c * 512]);
      gload_lds16(&Bt[(size_t)(n0 + row) * 1024 + k0 + lcol], &Bs[c * 512]);
    }
    __syncthreads();

#pragma unroll
    for (int kk = 0; kk < 2; ++kk) {
      s16x8 af[4], bf[4];
#pragma unroll
      for (int mi = 0; mi < 4; ++mi)
        af[mi] = *reinterpret_cast<const s16x8*>(
            &As[(wm * 64 + mi * 16 + l15) * BK + (((4 * kk + g) ^ rsw) * 8)]);
#pragma unroll
      for (int ni = 0; ni < 4; ++ni)
        bf[ni] = *reinterpret_cast<const s16x8*>(
            &Bs[(wn * 64 + ni * 16 + l15) * BK + (((4 * kk + g) ^ rsw) * 8)]);
#pragma unroll
      for (int mi = 0; mi < 4; ++mi)
#pragma unroll
        for (int ni = 0; ni < 4; ++ni)
          acc[mi][ni] = __builtin_amdgcn_mfma_f32_16x16x32_bf16(af[mi], bf[ni], acc[mi][ni], 0, 0, 0);
    }
    __syncthreads();
  }

  // C frag layout: col = l15, row = 4*g + reg
  if (mode == 0) {
    const int sel = n0 >> 10;          // whole block lives in one of Q/K/V
    const int nl0 = n0 & 1023;
    if (sel < 2) {
      unsigned short* outb = (unsigned short*)(sel == 0 ? out0 : out1);
      const float sc = (sel == 0) ? qscale : 1.0f;
#pragma unroll
      for (int mi = 0; mi < 4; ++mi) {
#pragma unroll
        for (int ni = 0; ni < 4; ++ni) {
          const int n = nl0 + wn * 64 + ni * 16 + l15;
          const int h = n >> 6, hd = n & 63;
#pragma unroll
          for (int r = 0; r < 4; ++r) {
            const int m = m0 + wm * 64 + mi * 16 + 4 * g + r;
            const int b = m >> 11, s = m & 2047;
            outb[(((b * H_ + h) * S_) + s) * HD_ + hd] = f2bf(acc[mi][ni][r] * sc);
          }
        }
      }
    } else {
      // V^T: out[((b*H+h)*HD + hd)*S + s]
      unsigned short* outb = (unsigned short*)out2;
#pragma unroll
      for (int mi = 0; mi < 4; ++mi) {
#pragma unroll
        for (int ni = 0; ni < 4; ++ni) {
          const int n = nl0 + wn * 64 + ni * 16 + l15;
          const int h = n >> 6, hd = n & 63;
          const int m = m0 + wm * 64 + mi * 16 + 4 * g;
          const int b = m >> 11, s = m & 2047;
          ushort4 o;
          o.x = f2bf(acc[mi][ni][0]);
          o.y = f2bf(acc[mi][ni][1]);
          o.z = f2bf(acc[mi][ni][2]);
          o.w = f2bf(acc[mi][ni][3]);
          *reinterpret_cast<ushort4*>(&outb[(((b * H_ + h) * HD_) + hd) * S_ + s]) = o;
        }
      }
    }
  } else {
    float* outf = (float*)out0;
#pragma unroll
    for (int mi = 0; mi < 4; ++mi) {
#pragma unroll
      for (int ni = 0; ni < 4; ++ni) {
        const int n = n0 + wn * 64 + ni * 16 + l15;
        const float bv = bias[n];
#pragma unroll
        for (int r = 0; r < 4; ++r) {
          const int m = m0 + wm * 64 + mi * 16 + 4 * g + r;
          outf[m * 1024 + n] = acc[mi][ni][r] + bv;
        }
      }
    }
  }
}

// ---------------- causal flash attention v9: fully barrier-free ----------------
// R14/R15 schedule (kv-split, chain<=16) with K AND V fragments loaded DIRECTLY from
// global (both R5-verified addressing patterns). No Kl, no Vl, no staging, and since
// Pl is per-wave-private: ZERO __syncthreads in the kernel. Each of the 4 waves
// free-runs its chain (break once past the diagonal); waves of a block share the
// L1-resident K/V tiles; latency hides via TLP across independent waves.
__global__ __launch_bounds__(256, 4) void attn_kernel(
    const unsigned short* __restrict__ Q,
    const unsigned short* __restrict__ K,
    const unsigned short* __restrict__ VT,
    unsigned short* __restrict__ Ctx,
    unsigned short* __restrict__ pctx,   // [512][128][64] bf16 raw partial ctx
    float* __restrict__ pml)             // [512][128][2] f32 (m, l)
{
  __shared__ unsigned short Pl[4][2][32][40];    // per-wave P^T halves (20.5 KB total)

  // chain-descending schedule: (qb, half) for qb>=8; half=-1 => whole-range block
  static const unsigned char QBv[24] = {15,15,7,14,14,13,13,6,12,12,11,11,5,10,10,9,9,4,8,8,3,2,1,0};
  static const signed char   HFv[24] = {0,1,-1,0,1,0,1,-1,0,1,0,1,-1,0,1,0,1,-1,0,1,-1,-1,-1,-1};

  const int t    = threadIdx.x;
  const int lane = t & 63;
  const int w    = t >> 6;        // 0..3
  const int q    = lane & 31;
  const int hi   = lane >> 5;

  const int bh = blockIdx.x;
  const int qb = QBv[blockIdx.y];
  const int hf = HFv[blockIdx.y];
  const long base  = (long)bh * S_ * HD_;
  const long vbase = (long)bh * HD_ * S_;
  const int q0w = qb * 128 + w * 32;         // this wave's first q-row

  int ktBeg, ktEnd;
  if (hf < 0) { ktBeg = 0; ktEnd = 2 * qb + 2; }
  else        { ktBeg = hf * (qb + 1); ktEnd = ktBeg + qb + 1; }

  // Q B-fragments: qf[s] = Q[q0w+q][16s + 8hi + j]
  s16x8 qf[4];
#pragma unroll
  for (int s = 0; s < 4; ++s)
    qf[s] = *reinterpret_cast<const s16x8*>(&Q[base + (long)(q0w + q) * HD_ + 16 * s + 8 * hi]);

  f32x16 ctx0, ctx1;
#pragma unroll
  for (int r = 0; r < 16; ++r) { ctx0[r] = 0.f; ctx1[r] = 0.f; }
  float m_run = -1e30f, l_run = 0.f;

  for (int kt = ktBeg; kt < ktEnd; ++kt) {
    const int kv64 = kt * 64;
    if (kv64 > q0w + 31) break;   // past this wave's diagonal: done forever (no barrier to keep)

    // ---- K and V^T fragments direct from global (L1/L2-resident; R5-verified) ----
    const unsigned short* Kt = &K[base + (long)kv64 * HD_];
    const unsigned short* Vp = &VT[vbase + kv64];
    s16x8 kb0[4], kb1[4], vf0[4], vf1[4];
#pragma unroll
    for (int s = 0; s < 4; ++s) {
      kb0[s] = *reinterpret_cast<const s16x8*>(&Kt[(q) * HD_ + 16 * s + 8 * hi]);
      kb1[s] = *reinterpret_cast<const s16x8*>(&Kt[(32 + q) * HD_ + 16 * s + 8 * hi]);
      vf0[s] = *reinterpret_cast<const s16x8*>(&Vp[(long)(q) * S_ + 16 * s + 8 * hi]);
      vf1[s] = *reinterpret_cast<const s16x8*>(&Vp[(long)(32 + q) * S_ + 16 * s + 8 * hi]);
    }

    // ---- QK^T: two 32x32 halves ----
    f32x16 sa0, sa1;
#pragma unroll
    for (int r = 0; r < 16; ++r) { sa0[r] = 0.f; sa1[r] = 0.f; }
    __builtin_amdgcn_s_setprio(1);
#pragma unroll
    for (int s = 0; s < 4; ++s)
      sa0 = __builtin_amdgcn_mfma_f32_32x32x16_bf16(kb0[s], qf[s], sa0, 0, 0, 0);
#pragma unroll
    for (int s = 0; s < 4; ++s)
      sa1 = __builtin_amdgcn_mfma_f32_32x32x16_bf16(kb1[s], qf[s], sa1, 0, 0, 0);
    __builtin_amdgcn_s_setprio(0);

    // ---- causal mask (half-0 split segments never reach the diagonal: guard is false)
    if (kv64 + 64 > q0w) {
#pragma unroll
      for (int r = 0; r < 16; ++r) {
        const int kl = (r & 3) + 8 * (r >> 2) + 4 * hi;
        if (kv64 + kl > q0w + q)      sa0[r] = -1e30f;
        if (kv64 + 32 + kl > q0w + q) sa1[r] = -1e30f;
      }
    }

    // ---- online softmax: in-lane tree + one cross-half shuffle; defer-max THR=8 ----
    float mx;
    {
      float a0 = fmaxf(fmaxf(sa0[0], sa0[1]), fmaxf(sa0[2], sa0[3]));
      float a1 = fmaxf(fmaxf(sa0[4], sa0[5]), fmaxf(sa0[6], sa0[7]));
      float a2 = fmaxf(fmaxf(sa0[8], sa0[9]), fmaxf(sa0[10], sa0[11]));
      float a3 = fmaxf(fmaxf(sa0[12], sa0[13]), fmaxf(sa0[14], sa0[15]));
      float b0 = fmaxf(fmaxf(sa1[0], sa1[1]), fmaxf(sa1[2], sa1[3]));
      float b1 = fmaxf(fmaxf(sa1[4], sa1[5]), fmaxf(sa1[6], sa1[7]));
      float b2 = fmaxf(fmaxf(sa1[8], sa1[9]), fmaxf(sa1[10], sa1[11]));
      float b3 = fmaxf(fmaxf(sa1[12], sa1[13]), fmaxf(sa1[14], sa1[15]));
      mx = fmaxf(fmaxf(fmaxf(a0, a1), fmaxf(a2, a3)), fmaxf(fmaxf(b0, b1), fmaxf(b2, b3)));
      mx = fmaxf(mx, __shfl_xor(mx, 32));
    }
    if (mx > m_run + 8.f) {          // rescale only on real max growth (T13)
      const float alpha = __builtin_amdgcn_exp2f(m_run - mx);
      m_run = mx;
      l_run *= alpha;
#pragma unroll
      for (int r = 0; r < 16; ++r) { ctx0[r] *= alpha; ctx1[r] *= alpha; }
    }

    float p0[16], p1[16];
#pragma unroll
    for (int r = 0; r < 16; ++r) {
      p0[r] = __builtin_amdgcn_exp2f(sa0[r] - m_run);
      p1[r] = __builtin_amdgcn_exp2f(sa1[r] - m_run);
    }
    float ps;
    {
      float s0 = ((p0[0] + p0[1]) + (p0[2] + p0[3])) + ((p0[4] + p0[5]) + (p0[6] + p0[7]));
      float s1 = ((p0[8] + p0[9]) + (p0[10] + p0[11])) + ((p0[12] + p0[13]) + (p0[14] + p0[15]));
      float s2 = ((p1[0] + p1[1]) + (p1[2] + p1[3])) + ((p1[4] + p1[5]) + (p1[6] + p1[7]));
      float s3 = ((p1[8] + p1[9]) + (p1[10] + p1[11])) + ((p1[12] + p1[13]) + (p1[14] + p1[15]));
      ps = (s0 + s1) + (s2 + s3);
      ps += __shfl_xor(ps, 32);
    }
    l_run += ps;

    // ---- P^T -> per-wave LDS (verified addressing), both halves ----
#pragma unroll
    for (int c = 0; c < 4; ++c) {
      unsigned int pk01, pk23;
      asm("v_cvt_pk_bf16_f32 %0, %1, %2" : "=v"(pk01) : "v"(p0[4 * c + 0]), "v"(p0[4 * c + 1]));
      asm("v_cvt_pk_bf16_f32 %0, %1, %2" : "=v"(pk23) : "v"(p0[4 * c + 2]), "v"(p0[4 * c + 3]));
      uint2 pr; pr.x = pk01; pr.y = pk23;
      *reinterpret_cast<uint2*>(&Pl[w][0][q][8 * c + 4 * hi]) = pr;
    }
#pragma unroll
    for (int c = 0; c < 4; ++c) {
      unsigned int pk01, pk23;
      asm("v_cvt_pk_bf16_f32 %0, %1, %2" : "=v"(pk01) : "v"(p1[4 * c + 0]), "v"(p1[4 * c + 1]));
      asm("v_cvt_pk_bf16_f32 %0, %1, %2" : "=v"(pk23) : "v"(p1[4 * c + 2]), "v"(p1[4 * c + 3]));
      uint2 pr; pr.x = pk01; pr.y = pk23;
      *reinterpret_cast<uint2*>(&Pl[w][1][q][8 * c + 4 * hi]) = pr;
    }

    // ---- PV: ctx^T[hd][q] += V^T[hd][k] * P[k][q], k = 16kc+8hi+j ----
    __builtin_amdgcn_s_setprio(1);
#pragma unroll
    for (int kc = 0; kc < 4; ++kc) {
      const s16x8 pf = *reinterpret_cast<const s16x8*>(&Pl[w][kc >> 1][q][16 * (kc & 1) + 8 * hi]);
      ctx0 = __builtin_amdgcn_mfma_f32_32x32x16_bf16(vf0[kc], pf, ctx0, 0, 0, 0);
      ctx1 = __builtin_amdgcn_mfma_f32_32x32x16_bf16(vf1[kc], pf, ctx1, 0, 0, 0);
    }
    __builtin_amdgcn_s_setprio(0);
  }

  if (hf < 0) {
    // ---- whole-range block: normalize + write Ctx directly ----
    const int b = bh >> 4, h = bh & 15;
    const float inv = 1.f / l_run;
    unsigned short* orow = &Ctx[((long)b * S_ + q0w + q) * D_ + h * 64];
#pragma unroll
    for (int c = 0; c < 4; ++c) {
      ushort4 o0, o1;
      o0.x = f2bf(ctx0[4 * c] * inv);     o0.y = f2bf(ctx0[4 * c + 1] * inv);
      o0.z = f2bf(ctx0[4 * c + 2] * inv); o0.w = f2bf(ctx0[4 * c + 3] * inv);
      o1.x = f2bf(ctx1[4 * c] * inv);     o1.y = f2bf(ctx1[4 * c + 1] * inv);
      o1.z = f2bf(ctx1[4 * c + 2] * inv); o1.w = f2bf(ctx1[4 * c + 3] * inv);
      *reinterpret_cast<ushort4*>(&orow[8 * c + 4 * hi])      = o0;
      *reinterpret_cast<ushort4*>(&orow[32 + 8 * c + 4 * hi]) = o1;
    }
  } else {
    // ---- split block: write raw partials (bf16 ctx + f32 m,l) ----
    const int sidx = ((bh << 3) + (qb - 8)) * 2 + hf;
    const int rloc = w * 32 + q;                       // row within the 128-row q-block
    unsigned short* prow = &pctx[((long)sidx * 128 + rloc) * 64];
#pragma unroll
    for (int c = 0; c < 4; ++c) {
      ushort4 o0, o1;
      o0.x = f2bf(ctx0[4 * c]);     o0.y = f2bf(ctx0[4 * c + 1]);
      o0.z = f2bf(ctx0[4 * c + 2]); o0.w = f2bf(ctx0[4 * c + 3]);
      o1.x = f2bf(ctx1[4 * c]);     o1.y = f2bf(ctx1[4 * c + 1]);
      o1.z = f2bf(ctx1[4 * c + 2]); o1.w = f2bf(ctx1[4 * c + 3]);
      *reinterpret_cast<ushort4*>(&prow[8 * c + 4 * hi])      = o0;
      *reinterpret_cast<ushort4*>(&prow[32 + 8 * c + 4 * hi]) = o1;
    }
    if (hi == 0) {
      pml[((long)sidx * 128 + rloc) * 2]     = m_run;
      pml[((long)sidx * 128 + rloc) * 2 + 1] = l_run;
    }
  }
}

// ---------------- merge of the two kv-half partials (qb 8..15) ----------------
__global__ __launch_bounds__(256) void merge_kernel(
    const unsigned short* __restrict__ pctx,
    const float* __restrict__ pml,
    unsigned short* __restrict__ Ctx)
{
  const int unit = blockIdx.x;          // 0..255: bh*8 + (qb-8)
  const int bh = unit >> 3;
  const int qb = (unit & 7) + 8;
  const long s0 = (long)unit * 2, s1 = s0 + 1;

  const int t   = threadIdx.x;
  const int row = t >> 1;               // 0..127
  const int hh  = t & 1;                // hd half: 0..31 / 32..63

  const long r0 = s0 * 128 + row;
  const long r1 = s1 * 128 + row;
  const float m0 = pml[r0 * 2], l0 = pml[r0 * 2 + 1];
  const float m1 = pml[r1 * 2], l1 = pml[r1 * 2 + 1];
  const float M  = fmaxf(m0, m1);
  const float a0 = __builtin_amdgcn_exp2f(m0 - M);
  const float a1 = __builtin_amdgcn_exp2f(m1 - M);
  const float inv = 1.f / (l0 * a0 + l1 * a1);

  const unsigned short* c0p = &pctx[r0 * 64 + hh * 32];
  const unsigned short* c1p = &pctx[r1 * 64 + hh * 32];
  const int b = bh >> 4, h = bh & 15;
  unsigned short* op = &Ctx[((long)b * S_ + qb * 128 + row) * D_ + h * 64 + hh * 32];

#pragma unroll
  for (int j = 0; j < 32; j += 8) {
    const s16x8 v0 = *reinterpret_cast<const s16x8*>(&c0p[j]);
    const s16x8 v1 = *reinterpret_cast<const s16x8*>(&c1p[j]);
    s16x8 o;
#pragma unroll
    for (int e = 0; e < 8; ++e) {
      const float f = (bf2f((unsigned short)v0[e]) * a0 + bf2f((unsigned short)v1[e]) * a1) * inv;
      o[e] = (short)f2bf(f);
    }
    *reinterpret_cast<s16x8*>(&op[j]) = o;
  }
}

// ---------------- launch ----------------
extern "C" void kernel_launch(void* const* d_in, const int* in_sizes, int n_in,
                              void* d_out, int out_size, void* d_ws, size_t ws_size,
                              hipStream_t stream) {
  const float* x  = (const float*)d_in[0];
  const float* Wq = (const float*)d_in[1];
  const float* Wk = (const float*)d_in[2];
  const float* Wv = (const float*)d_in[3];
  const float* Wo = (const float*)d_in[4];
  const float* bo = (const float*)d_in[5];
  float* out = (float*)d_out;

  char* ws = (char*)d_ws;
  const size_t MB = 1024 * 1024;
  unsigned short* xb  = (unsigned short*)(ws + 0 * MB);   // [4096][1024] bf16 (dead after QKV GEMM)
  unsigned short* WT  = (unsigned short*)(ws + 8 * MB);   // [3072][1024] bf16 (dead after QKV GEMM)
  unsigned short* Wob = (unsigned short*)(ws + 14 * MB);  // Wo[o][d] already B^T layout
  unsigned short* Qb  = (unsigned short*)(ws + 16 * MB);  // [B*H][S][HD]
  unsigned short* Kb  = (unsigned short*)(ws + 24 * MB);  // [B*H][S][HD]
  unsigned short* VTb = (unsigned short*)(ws + 32 * MB);  // [B*H][HD][S]
  unsigned short* Cx  = (unsigned short*)(ws + 40 * MB);  // [B][S][D] bf16
  // attn partials reuse regions dead by attn time:
  unsigned short* pctx = (unsigned short*)(ws + 0 * MB);  // [512][128][64] bf16 = 8 MB (over xb)
  float*          pml  = (float*)(ws + 8 * MB);           // [512][128][2] f32 = 0.5 MB (over WT)

  cvt_kernel<<<(M_ * D_ / 4 + 255) / 256, 256, 0, stream>>>(x, xb, M_ * D_ / 4);
  cvt_kernel<<<(D_ * D_ / 4 + 255) / 256, 256, 0, stream>>>(Wo, Wob, D_ * D_ / 4);
  transpose_cvt3<<<dim3(32, 32, 3), dim3(32, 8), 0, stream>>>(Wq, Wk, Wv, WT);

  // fused QKV projection: N = 3072, Q pre-scaled by HD^-0.5 * log2(e)
  gemm_bt<<<dim3(3 * D_ / BN, M_ / BM), 256, 0, stream>>>(
      xb, WT, (void*)Qb, (void*)Kb, (void*)VTb, nullptr, 0, 0.18033688011112042f);

  // kv-split attention: 768 blocks (chain-descending), then 256-block merge
  attn_kernel<<<dim3(B_ * H_, 24), 256, 0, stream>>>(Qb, Kb, VTb, Cx, pctx, pml);
  merge_kernel<<<256, 256, 0, stream>>>(pctx, pml, Cx);

  gemm_bt<<<dim3(D_ / BN, M_ / BM), 256, 0, stream>>>(
      Cx, Wob, (void*)out, nullptr, nullptr, bo, 1, 1.0f);
}

// Round 17
// 120.297 us; speedup vs baseline: 1.5067x; 1.5067x over previous
//
#include <hip/hip_runtime.h>

// Problem constants (fixed by the reference)
#define B_  2
#define S_  2048
#define D_  1024
#define H_  16
#define HD_ 64
#define M_  (B_*S_)   // 4096 rows in all GEMMs

typedef __attribute__((ext_vector_type(8))) short s16x8;    // 8 bf16 MFMA operand
typedef __attribute__((ext_vector_type(4))) float f32x4;
typedef __attribute__((ext_vector_type(16))) float f32x16;  // 32x32 MFMA accumulator

__device__ __forceinline__ unsigned short f2bf(float f) {
  unsigned int u = __builtin_bit_cast(unsigned int, f);
  u += 0x7fffu + ((u >> 16) & 1u);          // round-to-nearest-even
  return (unsigned short)(u >> 16);
}
__device__ __forceinline__ float bf2f(unsigned short h) {
  unsigned int u = ((unsigned int)h) << 16;
  return __builtin_bit_cast(float, u);
}

// async global->LDS, 16B per lane; LDS dest is wave-uniform base (HW adds lane*16)
__device__ __forceinline__ void gload_lds16(const unsigned short* g, unsigned short* l) {
  __builtin_amdgcn_global_load_lds((const __attribute__((address_space(1))) void*)g,
                                   (__attribute__((address_space(3))) void*)l, 16, 0, 0);
}

// ---------------- elementwise f32 -> bf16 (x4 vectorized) ----------------
__global__ void cvt_kernel(const float* __restrict__ in, unsigned short* __restrict__ out, int n4) {
  int i = blockIdx.x * blockDim.x + threadIdx.x;
  if (i >= n4) return;
  float4 v = reinterpret_cast<const float4*>(in)[i];
  ushort4 o;
  o.x = f2bf(v.x); o.y = f2bf(v.y); o.z = f2bf(v.z); o.w = f2bf(v.w);
  reinterpret_cast<ushort4*>(out)[i] = o;
}

// ---------------- 3x 1024x1024 transpose+convert in one dispatch ----------------
__global__ void transpose_cvt3(const float* __restrict__ W0, const float* __restrict__ W1,
                               const float* __restrict__ W2, unsigned short* __restrict__ dstBase) {
  __shared__ float tile[32][33];
  const float* in = blockIdx.z == 0 ? W0 : (blockIdx.z == 1 ? W1 : W2);
  unsigned short* out = dstBase + (size_t)blockIdx.z * 1024 * 1024;
  const int bx = blockIdx.x, by = blockIdx.y, tx = threadIdx.x;
  const int x = bx * 32 + tx;
  for (int j = threadIdx.y; j < 32; j += 8)
    tile[j][tx] = in[(by * 32 + j) * 1024 + x];
  __syncthreads();
  const int xo = by * 32 + tx;
  for (int j = threadIdx.y; j < 32; j += 8)
    out[(bx * 32 + j) * 1024 + xo] = f2bf(tile[tx][j]);
}

// ---------------- bf16 MFMA GEMM (global_load_lds staging + XOR-swizzled LDS) ----------------
// (round-8 verified: swizzle killed the 16-way ds_read conflict)
#define BM 128
#define BN 128
#define BK 64

__global__ __launch_bounds__(256, 4) void gemm_bt(
    const unsigned short* __restrict__ A,
    const unsigned short* __restrict__ Bt,
    void* __restrict__ out0, void* __restrict__ out1, void* __restrict__ out2,
    const float* __restrict__ bias,
    const int mode, const float qscale)
{
  __shared__ unsigned short As[BM * BK];
  __shared__ unsigned short Bs[BN * BK];

  const int t    = threadIdx.x;
  const int lane = t & 63;
  const int wid  = t >> 6;
  const int l15  = lane & 15;
  const int g    = lane >> 4;
  const int wm   = wid >> 1;   // 2x2 waves, each 64x64
  const int wn   = wid & 1;

  const int n0 = blockIdx.x * BN;
  const int m0 = blockIdx.y * BM;

  const int lrow = lane >> 3;                         // row within 8-row chunk
  const int lcol = ((lane & 7) ^ lrow) * 8;           // pre-swizzled source granule
  const int rsw  = l15 & 7;                           // read-side XOR key (row&7)

  f32x4 acc[4][4];
#pragma unroll
  for (int i = 0; i < 4; ++i)
#pragma unroll
    for (int j = 0; j < 4; ++j)
      acc[i][j] = (f32x4){0.f, 0.f, 0.f, 0.f};

  for (int kt = 0; kt < 1024 / BK; ++kt) {
    const int k0 = kt * BK;
#pragma unroll
    for (int p = 0; p < 4; ++p) {
      const int c = p * 4 + wid;            // wave-uniform chunk id (8 rows = 1KB)
      const int row = c * 8 + lrow;
      gload_lds16(&A[(size_t)(m0 + row) * 1024 + k0 + lcol], &As[c * 512]);
      gload_lds16(&Bt[(size_t)(n0 + row) * 1024 + k0 + lcol], &Bs[c * 512]);
    }
    __syncthreads();

#pragma unroll
    for (int kk = 0; kk < 2; ++kk) {
      s16x8 af[4], bf[4];
#pragma unroll
      for (int mi = 0; mi < 4; ++mi)
        af[mi] = *reinterpret_cast<const s16x8*>(
            &As[(wm * 64 + mi * 16 + l15) * BK + (((4 * kk + g) ^ rsw) * 8)]);
#pragma unroll
      for (int ni = 0; ni < 4; ++ni)
        bf[ni] = *reinterpret_cast<const s16x8*>(
            &Bs[(wn * 64 + ni * 16 + l15) * BK + (((4 * kk + g) ^ rsw) * 8)]);
#pragma unroll
      for (int mi = 0; mi < 4; ++mi)
#pragma unroll
        for (int ni = 0; ni < 4; ++ni)
          acc[mi][ni] = __builtin_amdgcn_mfma_f32_16x16x32_bf16(af[mi], bf[ni], acc[mi][ni], 0, 0, 0);
    }
    __syncthreads();
  }

  // C frag layout: col = l15, row = 4*g + reg
  if (mode == 0) {
    const int sel = n0 >> 10;          // whole block lives in one of Q/K/V
    const int nl0 = n0 & 1023;
    if (sel < 2) {
      unsigned short* outb = (unsigned short*)(sel == 0 ? out0 : out1);
      const float sc = (sel == 0) ? qscale : 1.0f;
#pragma unroll
      for (int mi = 0; mi < 4; ++mi) {
#pragma unroll
        for (int ni = 0; ni < 4; ++ni) {
          const int n = nl0 + wn * 64 + ni * 16 + l15;
          const int h = n >> 6, hd = n & 63;
#pragma unroll
          for (int r = 0; r < 4; ++r) {
            const int m = m0 + wm * 64 + mi * 16 + 4 * g + r;
            const int b = m >> 11, s = m & 2047;
            outb[(((b * H_ + h) * S_) + s) * HD_ + hd] = f2bf(acc[mi][ni][r] * sc);
          }
        }
      }
    } else {
      // V^T: out[((b*H+h)*HD + hd)*S + s]
      unsigned short* outb = (unsigned short*)out2;
#pragma unroll
      for (int mi = 0; mi < 4; ++mi) {
#pragma unroll
        for (int ni = 0; ni < 4; ++ni) {
          const int n = nl0 + wn * 64 + ni * 16 + l15;
          const int h = n >> 6, hd = n & 63;
          const int m = m0 + wm * 64 + mi * 16 + 4 * g;
          const int b = m >> 11, s = m & 2047;
          ushort4 o;
          o.x = f2bf(acc[mi][ni][0]);
          o.y = f2bf(acc[mi][ni][1]);
          o.z = f2bf(acc[mi][ni][2]);
          o.w = f2bf(acc[mi][ni][3]);
          *reinterpret_cast<ushort4*>(&outb[(((b * H_ + h) * HD_) + hd) * S_ + s]) = o;
        }
      }
    }
  } else {
    float* outf = (float*)out0;
#pragma unroll
    for (int mi = 0; mi < 4; ++mi) {
#pragma unroll
      for (int ni = 0; ni < 4; ++ni) {
        const int n = n0 + wn * 64 + ni * 16 + l15;
        const float bv = bias[n];
#pragma unroll
        for (int r = 0; r < 4; ++r) {
          const int m = m0 + wm * 64 + mi * 16 + 4 * g + r;
          outf[m * 1024 + n] = acc[mi][ni][r] + bv;
        }
      }
    }
  }
}

// ---------------- causal flash attention v6b: R14 mechanics + CU-balanced slot order ----------------
// Identical mechanics to the twice-verified R11/R14 kernel. ONLY change: the 24 (qb,half)
// slots are permuted across blockIdx.y so that, under linear round-robin block->CU
// assignment (blocks {c, c+256, c+512} share a CU), every CU's chain triple sums to 34:
// (16,16,2),(16,14,4),(15,13,6),(15,11,8),(14,11,9),(14,10,10),(13,12,9),(12,12,10).
// Pure launch-order permutation: sidx/merge depend only on (qb,half) -> correctness invariant.
__global__ __launch_bounds__(256) void attn_kernel(
    const unsigned short* __restrict__ Q,
    const unsigned short* __restrict__ K,
    const unsigned short* __restrict__ VT,
    unsigned short* __restrict__ Ctx,
    unsigned short* __restrict__ pctx,   // [512][128][64] bf16 raw partial ctx
    float* __restrict__ pml)             // [512][128][2] f32 (m, l)
{
  __shared__ unsigned short Kl[2][64 * 64];
  __shared__ unsigned short Vl[2][64 * 64];
  __shared__ unsigned short Pl[4][2][32][40];

  // balanced triples: y, y+8, y+16 land on the same CU; each triple sums to 34 tiles
  static const unsigned char QBv[24] = {15, 7,14,14,13,13,12,11,  15, 6,12,10,10, 9,11, 5,   0, 1, 2, 3, 8, 4, 8, 9};
  static const signed char   HFv[24] = { 0,-1, 0, 1, 0, 1, 1, 1,   1,-1, 0, 0, 1, 0, 0,-1,  -1,-1,-1,-1, 0,-1, 1, 1};

  const int t    = threadIdx.x;
  const int lane = t & 63;
  const int w    = t >> 6;        // 0..3
  const int q    = lane & 31;
  const int hi   = lane >> 5;

  const int bh = blockIdx.x;
  const int qb = QBv[blockIdx.y];
  const int hf = HFv[blockIdx.y];
  const long base  = (long)bh * S_ * HD_;
  const long vbase = (long)bh * HD_ * S_;
  const int q0w = qb * 128 + w * 32;         // this wave's first q-row

  int ktBeg, ktEnd;
  if (hf < 0) { ktBeg = 0; ktEnd = 2 * qb + 2; }
  else        { ktBeg = hf * (qb + 1); ktEnd = ktBeg + qb + 1; }

  // staging geometry: chunk = 8 rows (1KB); lane l -> row l>>3, swizzled granule (l&7)^(l>>3)
  const int srow = lane >> 3;
  const int scol = ((lane & 7) ^ srow) * 8;
  const int swz  = (q & 7) * 8;              // read-side XOR (shorts)

  // Q B-fragments: qf[s] = Q[q0w+q][16s + 8hi + j]
  s16x8 qf[4];
#pragma unroll
  for (int s = 0; s < 4; ++s)
    qf[s] = *reinterpret_cast<const s16x8*>(&Q[base + (long)(q0w + q) * HD_ + 16 * s + 8 * hi]);

  f32x16 ctx0, ctx1;
#pragma unroll
  for (int r = 0; r < 16; ++r) { ctx0[r] = 0.f; ctx1[r] = 0.f; }
  float m_run = -1e30f, l_run = 0.f;

  // prologue: stage tile ktBeg into buffer 0 (wave w stages chunks 2w, 2w+1)
#pragma unroll
  for (int p = 0; p < 2; ++p) {
    const int c = 2 * w + p;
    gload_lds16(&K[base + (long)(ktBeg * 64 + c * 8 + srow) * HD_ + scol], &Kl[0][c * 512]);
    gload_lds16(&VT[vbase + (long)(c * 8 + srow) * S_ + ktBeg * 64 + scol], &Vl[0][c * 512]);
  }
  __syncthreads();

  for (int kt = ktBeg; kt < ktEnd; ++kt) {
    const int cur  = (kt - ktBeg) & 1;
    const int kv64 = kt * 64;

    // issue next tile's staging FIRST (in flight under compute; barrier drains it)
    if (kt + 1 < ktEnd) {
      const int nk = (kt + 1) * 64;
#pragma unroll
      for (int p = 0; p < 2; ++p) {
        const int c = 2 * w + p;
        gload_lds16(&K[base + (long)(nk + c * 8 + srow) * HD_ + scol], &Kl[cur ^ 1][c * 512]);
        gload_lds16(&VT[vbase + (long)(c * 8 + srow) * S_ + nk + scol], &Vl[cur ^ 1][c * 512]);
      }
    }

    if (kv64 <= q0w + 31) {   // wave-uniform activity predicate
      // ---- QK^T: two 32x32 halves ----
      f32x16 sa0, sa1;
#pragma unroll
      for (int r = 0; r < 16; ++r) { sa0[r] = 0.f; sa1[r] = 0.f; }
      __builtin_amdgcn_s_setprio(1);
#pragma unroll
      for (int s = 0; s < 4; ++s) {
        const s16x8 kb0 = *reinterpret_cast<const s16x8*>(&Kl[cur][(q) * 64 + ((16 * s + 8 * hi) ^ swz)]);
        sa0 = __builtin_amdgcn_mfma_f32_32x32x16_bf16(kb0, qf[s], sa0, 0, 0, 0);
      }
#pragma unroll
      for (int s = 0; s < 4; ++s) {
        const s16x8 kb1 = *reinterpret_cast<const s16x8*>(&Kl[cur][(32 + q) * 64 + ((16 * s + 8 * hi) ^ swz)]);
        sa1 = __builtin_amdgcn_mfma_f32_32x32x16_bf16(kb1, qf[s], sa1, 0, 0, 0);
      }
      __builtin_amdgcn_s_setprio(0);

      // ---- causal mask (half-0 split segments never reach the diagonal: guard is false)
      if (kv64 + 64 > q0w) {
#pragma unroll
        for (int r = 0; r < 16; ++r) {
          const int kl = (r & 3) + 8 * (r >> 2) + 4 * hi;
          if (kv64 + kl > q0w + q)      sa0[r] = -1e30f;
          if (kv64 + 32 + kl > q0w + q) sa1[r] = -1e30f;
        }
      }

      // ---- online softmax: in-lane tree + one cross-half shuffle; defer-max THR=8 ----
      float mx;
      {
        float a0 = fmaxf(fmaxf(sa0[0], sa0[1]), fmaxf(sa0[2], sa0[3]));
        float a1 = fmaxf(fmaxf(sa0[4], sa0[5]), fmaxf(sa0[6], sa0[7]));
        float a2 = fmaxf(fmaxf(sa0[8], sa0[9]), fmaxf(sa0[10], sa0[11]));
        float a3 = fmaxf(fmaxf(sa0[12], sa0[13]), fmaxf(sa0[14], sa0[15]));
        float b0 = fmaxf(fmaxf(sa1[0], sa1[1]), fmaxf(sa1[2], sa1[3]));
        float b1 = fmaxf(fmaxf(sa1[4], sa1[5]), fmaxf(sa1[6], sa1[7]));
        float b2 = fmaxf(fmaxf(sa1[8], sa1[9]), fmaxf(sa1[10], sa1[11]));
        float b3 = fmaxf(fmaxf(sa1[12], sa1[13]), fmaxf(sa1[14], sa1[15]));
        mx = fmaxf(fmaxf(fmaxf(a0, a1), fmaxf(a2, a3)), fmaxf(fmaxf(b0, b1), fmaxf(b2, b3)));
        mx = fmaxf(mx, __shfl_xor(mx, 32));
      }
      if (mx > m_run + 8.f) {          // rescale only on real max growth (T13)
        const float alpha = __builtin_amdgcn_exp2f(m_run - mx);
        m_run = mx;
        l_run *= alpha;
#pragma unroll
        for (int r = 0; r < 16; ++r) { ctx0[r] *= alpha; ctx1[r] *= alpha; }
      }

      float p0[16], p1[16];
#pragma unroll
      for (int r = 0; r < 16; ++r) {
        p0[r] = __builtin_amdgcn_exp2f(sa0[r] - m_run);
        p1[r] = __builtin_amdgcn_exp2f(sa1[r] - m_run);
      }
      float ps;
      {
        float s0 = ((p0[0] + p0[1]) + (p0[2] + p0[3])) + ((p0[4] + p0[5]) + (p0[6] + p0[7]));
        float s1 = ((p0[8] + p0[9]) + (p0[10] + p0[11])) + ((p0[12] + p0[13]) + (p0[14] + p0[15]));
        float s2 = ((p1[0] + p1[1]) + (p1[2] + p1[3])) + ((p1[4] + p1[5]) + (p1[6] + p1[7]));
        float s3 = ((p1[8] + p1[9]) + (p1[10] + p1[11])) + ((p1[12] + p1[13]) + (p1[14] + p1[15]));
        ps = (s0 + s1) + (s2 + s3);
        ps += __shfl_xor(ps, 32);
      }
      l_run += ps;

      // ---- P^T -> per-wave LDS (verified addressing), both halves ----
#pragma unroll
      for (int c = 0; c < 4; ++c) {
        unsigned int pk01, pk23;
        asm("v_cvt_pk_bf16_f32 %0, %1, %2" : "=v"(pk01) : "v"(p0[4 * c + 0]), "v"(p0[4 * c + 1]));
        asm("v_cvt_pk_bf16_f32 %0, %1, %2" : "=v"(pk23) : "v"(p0[4 * c + 2]), "v"(p0[4 * c + 3]));
        uint2 pr; pr.x = pk01; pr.y = pk23;
        *reinterpret_cast<uint2*>(&Pl[w][0][q][8 * c + 4 * hi]) = pr;
      }
#pragma unroll
      for (int c = 0; c < 4; ++c) {
        unsigned int pk01, pk23;
        asm("v_cvt_pk_bf16_f32 %0, %1, %2" : "=v"(pk01) : "v"(p1[4 * c + 0]), "v"(p1[4 * c + 1]));
        asm("v_cvt_pk_bf16_f32 %0, %1, %2" : "=v"(pk23) : "v"(p1[4 * c + 2]), "v"(p1[4 * c + 3]));
        uint2 pr; pr.x = pk01; pr.y = pk23;
        *reinterpret_cast<uint2*>(&Pl[w][1][q][8 * c + 4 * hi]) = pr;
      }

      // ---- PV: ctx^T[hd][q] += V^T[hd][k] * P[k][q], k = 16kc+8hi+j ----
      __builtin_amdgcn_s_setprio(1);
#pragma unroll
      for (int kc = 0; kc < 4; ++kc) {
        const s16x8 pf = *reinterpret_cast<const s16x8*>(&Pl[w][kc >> 1][q][16 * (kc & 1) + 8 * hi]);
        const s16x8 v0 = *reinterpret_cast<const s16x8*>(&Vl[cur][(q) * 64 + ((16 * kc + 8 * hi) ^ swz)]);
        ctx0 = __builtin_amdgcn_mfma_f32_32x32x16_bf16(v0, pf, ctx0, 0, 0, 0);
        const s16x8 v1 = *reinterpret_cast<const s16x8*>(&Vl[cur][(32 + q) * 64 + ((16 * kc + 8 * hi) ^ swz)]);
        ctx1 = __builtin_amdgcn_mfma_f32_32x32x16_bf16(v1, pf, ctx1, 0, 0, 0);
      }
      __builtin_amdgcn_s_setprio(0);
    }

    __syncthreads();   // drains this iteration's staging; fences Kl/Vl reads before overwrite
  }

  if (hf < 0) {
    // ---- whole-range block: normalize + write Ctx directly ----
    const int b = bh >> 4, h = bh & 15;
    const float inv = 1.f / l_run;
    unsigned short* orow = &Ctx[((long)b * S_ + q0w + q) * D_ + h * 64];
#pragma unroll
    for (int c = 0; c < 4; ++c) {
      ushort4 o0, o1;
      o0.x = f2bf(ctx0[4 * c] * inv);     o0.y = f2bf(ctx0[4 * c + 1] * inv);
      o0.z = f2bf(ctx0[4 * c + 2] * inv); o0.w = f2bf(ctx0[4 * c + 3] * inv);
      o1.x = f2bf(ctx1[4 * c] * inv);     o1.y = f2bf(ctx1[4 * c + 1] * inv);
      o1.z = f2bf(ctx1[4 * c + 2] * inv); o1.w = f2bf(ctx1[4 * c + 3] * inv);
      *reinterpret_cast<ushort4*>(&orow[8 * c + 4 * hi])      = o0;
      *reinterpret_cast<ushort4*>(&orow[32 + 8 * c + 4 * hi]) = o1;
    }
  } else {
    // ---- split block: write raw partials (bf16 ctx + f32 m,l) ----
    const int sidx = ((bh << 3) + (qb - 8)) * 2 + hf;
    const int rloc = w * 32 + q;                       // row within the 128-row q-block
    unsigned short* prow = &pctx[((long)sidx * 128 + rloc) * 64];
#pragma unroll
    for (int c = 0; c < 4; ++c) {
      ushort4 o0, o1;
      o0.x = f2bf(ctx0[4 * c]);     o0.y = f2bf(ctx0[4 * c + 1]);
      o0.z = f2bf(ctx0[4 * c + 2]); o0.w = f2bf(ctx0[4 * c + 3]);
      o1.x = f2bf(ctx1[4 * c]);     o1.y = f2bf(ctx1[4 * c + 1]);
      o1.z = f2bf(ctx1[4 * c + 2]); o1.w = f2bf(ctx1[4 * c + 3]);
      *reinterpret_cast<ushort4*>(&prow[8 * c + 4 * hi])      = o0;
      *reinterpret_cast<ushort4*>(&prow[32 + 8 * c + 4 * hi]) = o1;
    }
    if (hi == 0) {
      pml[((long)sidx * 128 + rloc) * 2]     = m_run;
      pml[((long)sidx * 128 + rloc) * 2 + 1] = l_run;
    }
  }
}

// ---------------- merge of the two kv-half partials (qb 8..15) ----------------
__global__ __launch_bounds__(256) void merge_kernel(
    const unsigned short* __restrict__ pctx,
    const float* __restrict__ pml,
    unsigned short* __restrict__ Ctx)
{
  const int unit = blockIdx.x;          // 0..255: bh*8 + (qb-8)
  const int bh = unit >> 3;
  const int qb = (unit & 7) + 8;
  const long s0 = (long)unit * 2, s1 = s0 + 1;

  const int t   = threadIdx.x;
  const int row = t >> 1;               // 0..127
  const int hh  = t & 1;                // hd half: 0..31 / 32..63

  const long r0 = s0 * 128 + row;
  const long r1 = s1 * 128 + row;
  const float m0 = pml[r0 * 2], l0 = pml[r0 * 2 + 1];
  const float m1 = pml[r1 * 2], l1 = pml[r1 * 2 + 1];
  const float M  = fmaxf(m0, m1);
  const float a0 = __builtin_amdgcn_exp2f(m0 - M);
  const float a1 = __builtin_amdgcn_exp2f(m1 - M);
  const float inv = 1.f / (l0 * a0 + l1 * a1);

  const unsigned short* c0p = &pctx[r0 * 64 + hh * 32];
  const unsigned short* c1p = &pctx[r1 * 64 + hh * 32];
  const int b = bh >> 4, h = bh & 15;
  unsigned short* op = &Ctx[((long)b * S_ + qb * 128 + row) * D_ + h * 64 + hh * 32];

#pragma unroll
  for (int j = 0; j < 32; j += 8) {
    const s16x8 v0 = *reinterpret_cast<const s16x8*>(&c0p[j]);
    const s16x8 v1 = *reinterpret_cast<const s16x8*>(&c1p[j]);
    s16x8 o;
#pragma unroll
    for (int e = 0; e < 8; ++e) {
      const float f = (bf2f((unsigned short)v0[e]) * a0 + bf2f((unsigned short)v1[e]) * a1) * inv;
      o[e] = (short)f2bf(f);
    }
    *reinterpret_cast<s16x8*>(&op[j]) = o;
  }
}

// ---------------- launch ----------------
extern "C" void kernel_launch(void* const* d_in, const int* in_sizes, int n_in,
                              void* d_out, int out_size, void* d_ws, size_t ws_size,
                              hipStream_t stream) {
  const float* x  = (const float*)d_in[0];
  const float* Wq = (const float*)d_in[1];
  const float* Wk = (const float*)d_in[2];
  const float* Wv = (const float*)d_in[3];
  const float* Wo = (const float*)d_in[4];
  const float* bo = (const float*)d_in[5];
  float* out = (float*)d_out;

  char* ws = (char*)d_ws;
  const size_t MB = 1024 * 1024;
  unsigned short* xb  = (unsigned short*)(ws + 0 * MB);   // [4096][1024] bf16 (dead after QKV GEMM)
  unsigned short* WT  = (unsigned short*)(ws + 8 * MB);   // [3072][1024] bf16 (dead after QKV GEMM)
  unsigned short* Wob = (unsigned short*)(ws + 14 * MB);  // Wo[o][d] already B^T layout
  unsigned short* Qb  = (unsigned short*)(ws + 16 * MB);  // [B*H][S][HD]
  unsigned short* Kb  = (unsigned short*)(ws + 24 * MB);  // [B*H][S][HD]
  unsigned short* VTb = (unsigned short*)(ws + 32 * MB);  // [B*H][HD][S]
  unsigned short* Cx  = (unsigned short*)(ws + 40 * MB);  // [B][S][D] bf16
  // attn partials reuse regions dead by attn time:
  unsigned short* pctx = (unsigned short*)(ws + 0 * MB);  // [512][128][64] bf16 = 8 MB (over xb)
  float*          pml  = (float*)(ws + 8 * MB);           // [512][128][2] f32 = 0.5 MB (over WT)

  cvt_kernel<<<(M_ * D_ / 4 + 255) / 256, 256, 0, stream>>>(x, xb, M_ * D_ / 4);
  cvt_kernel<<<(D_ * D_ / 4 + 255) / 256, 256, 0, stream>>>(Wo, Wob, D_ * D_ / 4);
  transpose_cvt3<<<dim3(32, 32, 3), dim3(32, 8), 0, stream>>>(Wq, Wk, Wv, WT);

  // fused QKV projection: N = 3072, Q pre-scaled by HD^-0.5 * log2(e)
  gemm_bt<<<dim3(3 * D_ / BN, M_ / BM), 256, 0, stream>>>(
      xb, WT, (void*)Qb, (void*)Kb, (void*)VTb, nullptr, 0, 0.18033688011112042f);

  // kv-split attention: 768 blocks (CU-balanced slot order), then 256-block merge
  attn_kernel<<<dim3(B_ * H_, 24), 256, 0, stream>>>(Qb, Kb, VTb, Cx, pctx, pml);
  merge_kernel<<<256, 256, 0, stream>>>(pctx, pml, Cx);

  gemm_bt<<<dim3(D_ / BN, M_ / BM), 256, 0, stream>>>(
      Cx, Wob, (void*)out, nullptr, nullptr, bo, 1, 1.0f);
}

// Round 18
// 116.136 us; speedup vs baseline: 1.5607x; 1.0358x over previous
//
#include <hip/hip_runtime.h>

// Problem constants (fixed by the reference)
#define B_  2
#define S_  2048
#define D_  1024
#define H_  16
#define HD_ 64
#define M_  (B_*S_)   // 4096 rows in all GEMMs

typedef __attribute__((ext_vector_type(8))) short s16x8;    // 8 bf16 MFMA operand
typedef __attribute__((ext_vector_type(4))) float f32x4;
typedef __attribute__((ext_vector_type(16))) float f32x16;  // 32x32 MFMA accumulator

__device__ __forceinline__ unsigned short f2bf(float f) {
  unsigned int u = __builtin_bit_cast(unsigned int, f);
  u += 0x7fffu + ((u >> 16) & 1u);          // round-to-nearest-even
  return (unsigned short)(u >> 16);
}
__device__ __forceinline__ float bf2f(unsigned short h) {
  unsigned int u = ((unsigned int)h) << 16;
  return __builtin_bit_cast(float, u);
}

// async global->LDS, 16B per lane; LDS dest is wave-uniform base (HW adds lane*16)
__device__ __forceinline__ void gload_lds16(const unsigned short* g, unsigned short* l) {
  __builtin_amdgcn_global_load_lds((const __attribute__((address_space(1))) void*)g,
                                   (__attribute__((address_space(3))) void*)l, 16, 0, 0);
}

// ---------------- elementwise f32 -> bf16 (x4 vectorized) ----------------
__global__ void cvt_kernel(const float* __restrict__ in, unsigned short* __restrict__ out, int n4) {
  int i = blockIdx.x * blockDim.x + threadIdx.x;
  if (i >= n4) return;
  float4 v = reinterpret_cast<const float4*>(in)[i];
  ushort4 o;
  o.x = f2bf(v.x); o.y = f2bf(v.y); o.z = f2bf(v.z); o.w = f2bf(v.w);
  reinterpret_cast<ushort4*>(out)[i] = o;
}

// ---------------- 3x 1024x1024 transpose+convert in one dispatch ----------------
__global__ void transpose_cvt3(const float* __restrict__ W0, const float* __restrict__ W1,
                               const float* __restrict__ W2, unsigned short* __restrict__ dstBase) {
  __shared__ float tile[32][33];
  const float* in = blockIdx.z == 0 ? W0 : (blockIdx.z == 1 ? W1 : W2);
  unsigned short* out = dstBase + (size_t)blockIdx.z * 1024 * 1024;
  const int bx = blockIdx.x, by = blockIdx.y, tx = threadIdx.x;
  const int x = bx * 32 + tx;
  for (int j = threadIdx.y; j < 32; j += 8)
    tile[j][tx] = in[(by * 32 + j) * 1024 + x];
  __syncthreads();
  const int xo = by * 32 + tx;
  for (int j = threadIdx.y; j < 32; j += 8)
    out[(bx * 32 + j) * 1024 + xo] = f2bf(tile[tx][j]);
}

// ---------------- bf16 MFMA GEMM (global_load_lds staging + XOR-swizzled LDS) ----------------
// (round-8 verified: swizzle killed the 16-way ds_read conflict)
#define BM 128
#define BN 128
#define BK 64

__global__ __launch_bounds__(256, 4) void gemm_bt(
    const unsigned short* __restrict__ A,
    const unsigned short* __restrict__ Bt,
    void* __restrict__ out0, void* __restrict__ out1, void* __restrict__ out2,
    const float* __restrict__ bias,
    const int mode, const float qscale)
{
  __shared__ unsigned short As[BM * BK];
  __shared__ unsigned short Bs[BN * BK];

  const int t    = threadIdx.x;
  const int lane = t & 63;
  const int wid  = t >> 6;
  const int l15  = lane & 15;
  const int g    = lane >> 4;
  const int wm   = wid >> 1;   // 2x2 waves, each 64x64
  const int wn   = wid & 1;

  const int n0 = blockIdx.x * BN;
  const int m0 = blockIdx.y * BM;

  const int lrow = lane >> 3;                         // row within 8-row chunk
  const int lcol = ((lane & 7) ^ lrow) * 8;           // pre-swizzled source granule
  const int rsw  = l15 & 7;                           // read-side XOR key (row&7)

  f32x4 acc[4][4];
#pragma unroll
  for (int i = 0; i < 4; ++i)
#pragma unroll
    for (int j = 0; j < 4; ++j)
      acc[i][j] = (f32x4){0.f, 0.f, 0.f, 0.f};

  for (int kt = 0; kt < 1024 / BK; ++kt) {
    const int k0 = kt * BK;
#pragma unroll
    for (int p = 0; p < 4; ++p) {
      const int c = p * 4 + wid;            // wave-uniform chunk id (8 rows = 1KB)
      const int row = c * 8 + lrow;
      gload_lds16(&A[(size_t)(m0 + row) * 1024 + k0 + lcol], &As[c * 512]);
      gload_lds16(&Bt[(size_t)(n0 + row) * 1024 + k0 + lcol], &Bs[c * 512]);
    }
    __syncthreads();

#pragma unroll
    for (int kk = 0; kk < 2; ++kk) {
      s16x8 af[4], bf[4];
#pragma unroll
      for (int mi = 0; mi < 4; ++mi)
        af[mi] = *reinterpret_cast<const s16x8*>(
            &As[(wm * 64 + mi * 16 + l15) * BK + (((4 * kk + g) ^ rsw) * 8)]);
#pragma unroll
      for (int ni = 0; ni < 4; ++ni)
        bf[ni] = *reinterpret_cast<const s16x8*>(
            &Bs[(wn * 64 + ni * 16 + l15) * BK + (((4 * kk + g) ^ rsw) * 8)]);
#pragma unroll
      for (int mi = 0; mi < 4; ++mi)
#pragma unroll
        for (int ni = 0; ni < 4; ++ni)
          acc[mi][ni] = __builtin_amdgcn_mfma_f32_16x16x32_bf16(af[mi], bf[ni], acc[mi][ni], 0, 0, 0);
    }
    __syncthreads();
  }

  // C frag layout: col = l15, row = 4*g + reg
  if (mode == 0) {
    const int sel = n0 >> 10;          // whole block lives in one of Q/K/V
    const int nl0 = n0 & 1023;
    if (sel < 2) {
      unsigned short* outb = (unsigned short*)(sel == 0 ? out0 : out1);
      const float sc = (sel == 0) ? qscale : 1.0f;
#pragma unroll
      for (int mi = 0; mi < 4; ++mi) {
#pragma unroll
        for (int ni = 0; ni < 4; ++ni) {
          const int n = nl0 + wn * 64 + ni * 16 + l15;
          const int h = n >> 6, hd = n & 63;
#pragma unroll
          for (int r = 0; r < 4; ++r) {
            const int m = m0 + wm * 64 + mi * 16 + 4 * g + r;
            const int b = m >> 11, s = m & 2047;
            outb[(((b * H_ + h) * S_) + s) * HD_ + hd] = f2bf(acc[mi][ni][r] * sc);
          }
        }
      }
    } else {
      // V^T: out[((b*H+h)*HD + hd)*S + s]
      unsigned short* outb = (unsigned short*)out2;
#pragma unroll
      for (int mi = 0; mi < 4; ++mi) {
#pragma unroll
        for (int ni = 0; ni < 4; ++ni) {
          const int n = nl0 + wn * 64 + ni * 16 + l15;
          const int h = n >> 6, hd = n & 63;
          const int m = m0 + wm * 64 + mi * 16 + 4 * g;
          const int b = m >> 11, s = m & 2047;
          ushort4 o;
          o.x = f2bf(acc[mi][ni][0]);
          o.y = f2bf(acc[mi][ni][1]);
          o.z = f2bf(acc[mi][ni][2]);
          o.w = f2bf(acc[mi][ni][3]);
          *reinterpret_cast<ushort4*>(&outb[(((b * H_ + h) * HD_) + hd) * S_ + s]) = o;
        }
      }
    }
  } else {
    float* outf = (float*)out0;
#pragma unroll
    for (int mi = 0; mi < 4; ++mi) {
#pragma unroll
      for (int ni = 0; ni < 4; ++ni) {
        const int n = n0 + wn * 64 + ni * 16 + l15;
        const float bv = bias[n];
#pragma unroll
        for (int r = 0; r < 4; ++r) {
          const int m = m0 + wm * 64 + mi * 16 + 4 * g + r;
          outf[m * 1024 + n] = acc[mi][ni][r] + bv;
        }
      }
    }
  }
}

// ---------------- causal flash attention v6 (R11/R14-verified): kv-split long blocks ----------------
// Block = 4 waves x 32 q-rows. qb<=7 whole-range (chain <= 16); qb>=8 split into
// (qb,half) pairs, each owning kv tiles [h*(qb+1),(h+1)*(qb+1)) — chain qb+1 <= 16 —
// writing raw partials (ctx bf16, m, l); merge_kernel combines. 768 blocks = 3/CU,
// chain-descending launch order (best-measured; CU-level balancing refuted R9/R12/R17).
__global__ __launch_bounds__(256) void attn_kernel(
    const unsigned short* __restrict__ Q,
    const unsigned short* __restrict__ K,
    const unsigned short* __restrict__ VT,
    unsigned short* __restrict__ Ctx,
    unsigned short* __restrict__ pctx,   // [512][128][64] bf16 raw partial ctx
    float* __restrict__ pml)             // [512][128][2] f32 (m, l)
{
  __shared__ unsigned short Kl[2][64 * 64];
  __shared__ unsigned short Vl[2][64 * 64];
  __shared__ unsigned short Pl[4][2][32][40];

  // chain-descending schedule: (qb, half) for qb>=8; half=-1 => whole-range block
  static const unsigned char QBv[24] = {15,15,7,14,14,13,13,6,12,12,11,11,5,10,10,9,9,4,8,8,3,2,1,0};
  static const signed char   HFv[24] = {0,1,-1,0,1,0,1,-1,0,1,0,1,-1,0,1,0,1,-1,0,1,-1,-1,-1,-1};

  const int t    = threadIdx.x;
  const int lane = t & 63;
  const int w    = t >> 6;        // 0..3
  const int q    = lane & 31;
  const int hi   = lane >> 5;

  const int bh = blockIdx.x;
  const int qb = QBv[blockIdx.y];
  const int hf = HFv[blockIdx.y];
  const long base  = (long)bh * S_ * HD_;
  const long vbase = (long)bh * HD_ * S_;
  const int q0w = qb * 128 + w * 32;         // this wave's first q-row

  int ktBeg, ktEnd;
  if (hf < 0) { ktBeg = 0; ktEnd = 2 * qb + 2; }
  else        { ktBeg = hf * (qb + 1); ktEnd = ktBeg + qb + 1; }

  // staging geometry: chunk = 8 rows (1KB); lane l -> row l>>3, swizzled granule (l&7)^(l>>3)
  const int srow = lane >> 3;
  const int scol = ((lane & 7) ^ srow) * 8;
  const int swz  = (q & 7) * 8;              // read-side XOR (shorts)

  // Q B-fragments: qf[s] = Q[q0w+q][16s + 8hi + j]
  s16x8 qf[4];
#pragma unroll
  for (int s = 0; s < 4; ++s)
    qf[s] = *reinterpret_cast<const s16x8*>(&Q[base + (long)(q0w + q) * HD_ + 16 * s + 8 * hi]);

  f32x16 ctx0, ctx1;
#pragma unroll
  for (int r = 0; r < 16; ++r) { ctx0[r] = 0.f; ctx1[r] = 0.f; }
  float m_run = -1e30f, l_run = 0.f;

  // prologue: stage tile ktBeg into buffer 0 (wave w stages chunks 2w, 2w+1)
#pragma unroll
  for (int p = 0; p < 2; ++p) {
    const int c = 2 * w + p;
    gload_lds16(&K[base + (long)(ktBeg * 64 + c * 8 + srow) * HD_ + scol], &Kl[0][c * 512]);
    gload_lds16(&VT[vbase + (long)(c * 8 + srow) * S_ + ktBeg * 64 + scol], &Vl[0][c * 512]);
  }
  __syncthreads();

  for (int kt = ktBeg; kt < ktEnd; ++kt) {
    const int cur  = (kt - ktBeg) & 1;
    const int kv64 = kt * 64;

    // issue next tile's staging FIRST (in flight under compute; barrier drains it)
    if (kt + 1 < ktEnd) {
      const int nk = (kt + 1) * 64;
#pragma unroll
      for (int p = 0; p < 2; ++p) {
        const int c = 2 * w + p;
        gload_lds16(&K[base + (long)(nk + c * 8 + srow) * HD_ + scol], &Kl[cur ^ 1][c * 512]);
        gload_lds16(&VT[vbase + (long)(c * 8 + srow) * S_ + nk + scol], &Vl[cur ^ 1][c * 512]);
      }
    }

    if (kv64 <= q0w + 31) {   // wave-uniform activity predicate
      // ---- QK^T: two 32x32 halves ----
      f32x16 sa0, sa1;
#pragma unroll
      for (int r = 0; r < 16; ++r) { sa0[r] = 0.f; sa1[r] = 0.f; }
      __builtin_amdgcn_s_setprio(1);
#pragma unroll
      for (int s = 0; s < 4; ++s) {
        const s16x8 kb0 = *reinterpret_cast<const s16x8*>(&Kl[cur][(q) * 64 + ((16 * s + 8 * hi) ^ swz)]);
        sa0 = __builtin_amdgcn_mfma_f32_32x32x16_bf16(kb0, qf[s], sa0, 0, 0, 0);
      }
#pragma unroll
      for (int s = 0; s < 4; ++s) {
        const s16x8 kb1 = *reinterpret_cast<const s16x8*>(&Kl[cur][(32 + q) * 64 + ((16 * s + 8 * hi) ^ swz)]);
        sa1 = __builtin_amdgcn_mfma_f32_32x32x16_bf16(kb1, qf[s], sa1, 0, 0, 0);
      }
      __builtin_amdgcn_s_setprio(0);

      // ---- causal mask (half-0 split segments never reach the diagonal: guard is false)
      if (kv64 + 64 > q0w) {
#pragma unroll
        for (int r = 0; r < 16; ++r) {
          const int kl = (r & 3) + 8 * (r >> 2) + 4 * hi;
          if (kv64 + kl > q0w + q)      sa0[r] = -1e30f;
          if (kv64 + 32 + kl > q0w + q) sa1[r] = -1e30f;
        }
      }

      // ---- online softmax: in-lane tree + one cross-half shuffle; defer-max THR=8 ----
      float mx;
      {
        float a0 = fmaxf(fmaxf(sa0[0], sa0[1]), fmaxf(sa0[2], sa0[3]));
        float a1 = fmaxf(fmaxf(sa0[4], sa0[5]), fmaxf(sa0[6], sa0[7]));
        float a2 = fmaxf(fmaxf(sa0[8], sa0[9]), fmaxf(sa0[10], sa0[11]));
        float a3 = fmaxf(fmaxf(sa0[12], sa0[13]), fmaxf(sa0[14], sa0[15]));
        float b0 = fmaxf(fmaxf(sa1[0], sa1[1]), fmaxf(sa1[2], sa1[3]));
        float b1 = fmaxf(fmaxf(sa1[4], sa1[5]), fmaxf(sa1[6], sa1[7]));
        float b2 = fmaxf(fmaxf(sa1[8], sa1[9]), fmaxf(sa1[10], sa1[11]));
        float b3 = fmaxf(fmaxf(sa1[12], sa1[13]), fmaxf(sa1[14], sa1[15]));
        mx = fmaxf(fmaxf(fmaxf(a0, a1), fmaxf(a2, a3)), fmaxf(fmaxf(b0, b1), fmaxf(b2, b3)));
        mx = fmaxf(mx, __shfl_xor(mx, 32));
      }
      if (mx > m_run + 8.f) {          // rescale only on real max growth (T13)
        const float alpha = __builtin_amdgcn_exp2f(m_run - mx);
        m_run = mx;
        l_run *= alpha;
#pragma unroll
        for (int r = 0; r < 16; ++r) { ctx0[r] *= alpha; ctx1[r] *= alpha; }
      }

      float p0[16], p1[16];
#pragma unroll
      for (int r = 0; r < 16; ++r) {
        p0[r] = __builtin_amdgcn_exp2f(sa0[r] - m_run);
        p1[r] = __builtin_amdgcn_exp2f(sa1[r] - m_run);
      }
      float ps;
      {
        float s0 = ((p0[0] + p0[1]) + (p0[2] + p0[3])) + ((p0[4] + p0[5]) + (p0[6] + p0[7]));
        float s1 = ((p0[8] + p0[9]) + (p0[10] + p0[11])) + ((p0[12] + p0[13]) + (p0[14] + p0[15]));
        float s2 = ((p1[0] + p1[1]) + (p1[2] + p1[3])) + ((p1[4] + p1[5]) + (p1[6] + p1[7]));
        float s3 = ((p1[8] + p1[9]) + (p1[10] + p1[11])) + ((p1[12] + p1[13]) + (p1[14] + p1[15]));
        ps = (s0 + s1) + (s2 + s3);
        ps += __shfl_xor(ps, 32);
      }
      l_run += ps;

      // ---- P^T -> per-wave LDS (verified addressing), both halves ----
#pragma unroll
      for (int c = 0; c < 4; ++c) {
        unsigned int pk01, pk23;
        asm("v_cvt_pk_bf16_f32 %0, %1, %2" : "=v"(pk01) : "v"(p0[4 * c + 0]), "v"(p0[4 * c + 1]));
        asm("v_cvt_pk_bf16_f32 %0, %1, %2" : "=v"(pk23) : "v"(p0[4 * c + 2]), "v"(p0[4 * c + 3]));
        uint2 pr; pr.x = pk01; pr.y = pk23;
        *reinterpret_cast<uint2*>(&Pl[w][0][q][8 * c + 4 * hi]) = pr;
      }
#pragma unroll
      for (int c = 0; c < 4; ++c) {
        unsigned int pk01, pk23;
        asm("v_cvt_pk_bf16_f32 %0, %1, %2" : "=v"(pk01) : "v"(p1[4 * c + 0]), "v"(p1[4 * c + 1]));
        asm("v_cvt_pk_bf16_f32 %0, %1, %2" : "=v"(pk23) : "v"(p1[4 * c + 2]), "v"(p1[4 * c + 3]));
        uint2 pr; pr.x = pk01; pr.y = pk23;
        *reinterpret_cast<uint2*>(&Pl[w][1][q][8 * c + 4 * hi]) = pr;
      }

      // ---- PV: ctx^T[hd][q] += V^T[hd][k] * P[k][q], k = 16kc+8hi+j ----
      __builtin_amdgcn_s_setprio(1);
#pragma unroll
      for (int kc = 0; kc < 4; ++kc) {
        const s16x8 pf = *reinterpret_cast<const s16x8*>(&Pl[w][kc >> 1][q][16 * (kc & 1) + 8 * hi]);
        const s16x8 v0 = *reinterpret_cast<const s16x8*>(&Vl[cur][(q) * 64 + ((16 * kc + 8 * hi) ^ swz)]);
        ctx0 = __builtin_amdgcn_mfma_f32_32x32x16_bf16(v0, pf, ctx0, 0, 0, 0);
        const s16x8 v1 = *reinterpret_cast<const s16x8*>(&Vl[cur][(32 + q) * 64 + ((16 * kc + 8 * hi) ^ swz)]);
        ctx1 = __builtin_amdgcn_mfma_f32_32x32x16_bf16(v1, pf, ctx1, 0, 0, 0);
      }
      __builtin_amdgcn_s_setprio(0);
    }

    __syncthreads();   // drains this iteration's staging; fences Kl/Vl reads before overwrite
  }

  if (hf < 0) {
    // ---- whole-range block: normalize + write Ctx directly ----
    const int b = bh >> 4, h = bh & 15;
    const float inv = 1.f / l_run;
    unsigned short* orow = &Ctx[((long)b * S_ + q0w + q) * D_ + h * 64];
#pragma unroll
    for (int c = 0; c < 4; ++c) {
      ushort4 o0, o1;
      o0.x = f2bf(ctx0[4 * c] * inv);     o0.y = f2bf(ctx0[4 * c + 1] * inv);
      o0.z = f2bf(ctx0[4 * c + 2] * inv); o0.w = f2bf(ctx0[4 * c + 3] * inv);
      o1.x = f2bf(ctx1[4 * c] * inv);     o1.y = f2bf(ctx1[4 * c + 1] * inv);
      o1.z = f2bf(ctx1[4 * c + 2] * inv); o1.w = f2bf(ctx1[4 * c + 3] * inv);
      *reinterpret_cast<ushort4*>(&orow[8 * c + 4 * hi])      = o0;
      *reinterpret_cast<ushort4*>(&orow[32 + 8 * c + 4 * hi]) = o1;
    }
  } else {
    // ---- split block: write raw partials (bf16 ctx + f32 m,l) ----
    const int sidx = ((bh << 3) + (qb - 8)) * 2 + hf;
    const int rloc = w * 32 + q;                       // row within the 128-row q-block
    unsigned short* prow = &pctx[((long)sidx * 128 + rloc) * 64];
#pragma unroll
    for (int c = 0; c < 4; ++c) {
      ushort4 o0, o1;
      o0.x = f2bf(ctx0[4 * c]);     o0.y = f2bf(ctx0[4 * c + 1]);
      o0.z = f2bf(ctx0[4 * c + 2]); o0.w = f2bf(ctx0[4 * c + 3]);
      o1.x = f2bf(ctx1[4 * c]);     o1.y = f2bf(ctx1[4 * c + 1]);
      o1.z = f2bf(ctx1[4 * c + 2]); o1.w = f2bf(ctx1[4 * c + 3]);
      *reinterpret_cast<ushort4*>(&prow[8 * c + 4 * hi])      = o0;
      *reinterpret_cast<ushort4*>(&prow[32 + 8 * c + 4 * hi]) = o1;
    }
    if (hi == 0) {
      pml[((long)sidx * 128 + rloc) * 2]     = m_run;
      pml[((long)sidx * 128 + rloc) * 2 + 1] = l_run;
    }
  }
}

// ---------------- merge of the two kv-half partials (qb 8..15) ----------------
__global__ __launch_bounds__(256) void merge_kernel(
    const unsigned short* __restrict__ pctx,
    const float* __restrict__ pml,
    unsigned short* __restrict__ Ctx)
{
  const int unit = blockIdx.x;          // 0..255: bh*8 + (qb-8)
  const int bh = unit >> 3;
  const int qb = (unit & 7) + 8;
  const long s0 = (long)unit * 2, s1 = s0 + 1;

  const int t   = threadIdx.x;
  const int row = t >> 1;               // 0..127
  const int hh  = t & 1;                // hd half: 0..31 / 32..63

  const long r0 = s0 * 128 + row;
  const long r1 = s1 * 128 + row;
  const float m0 = pml[r0 * 2], l0 = pml[r0 * 2 + 1];
  const float m1 = pml[r1 * 2], l1 = pml[r1 * 2 + 1];
  const float M  = fmaxf(m0, m1);
  const float a0 = __builtin_amdgcn_exp2f(m0 - M);
  const float a1 = __builtin_amdgcn_exp2f(m1 - M);
  const float inv = 1.f / (l0 * a0 + l1 * a1);

  const unsigned short* c0p = &pctx[r0 * 64 + hh * 32];
  const unsigned short* c1p = &pctx[r1 * 64 + hh * 32];
  const int b = bh >> 4, h = bh & 15;
  unsigned short* op = &Ctx[((long)b * S_ + qb * 128 + row) * D_ + h * 64 + hh * 32];

#pragma unroll
  for (int j = 0; j < 32; j += 8) {
    const s16x8 v0 = *reinterpret_cast<const s16x8*>(&c0p[j]);
    const s16x8 v1 = *reinterpret_cast<const s16x8*>(&c1p[j]);
    s16x8 o;
#pragma unroll
    for (int e = 0; e < 8; ++e) {
      const float f = (bf2f((unsigned short)v0[e]) * a0 + bf2f((unsigned short)v1[e]) * a1) * inv;
      o[e] = (short)f2bf(f);
    }
    *reinterpret_cast<s16x8*>(&op[j]) = o;
  }
}

// ---------------- launch ----------------
extern "C" void kernel_launch(void* const* d_in, const int* in_sizes, int n_in,
                              void* d_out, int out_size, void* d_ws, size_t ws_size,
                              hipStream_t stream) {
  const float* x  = (const float*)d_in[0];
  const float* Wq = (const float*)d_in[1];
  const float* Wk = (const float*)d_in[2];
  const float* Wv = (const float*)d_in[3];
  const float* Wo = (const float*)d_in[4];
  const float* bo = (const float*)d_in[5];
  float* out = (float*)d_out;

  char* ws = (char*)d_ws;
  const size_t MB = 1024 * 1024;
  unsigned short* xb  = (unsigned short*)(ws + 0 * MB);   // [4096][1024] bf16 (dead after QKV GEMM)
  unsigned short* WT  = (unsigned short*)(ws + 8 * MB);   // [3072][1024] bf16 (dead after QKV GEMM)
  unsigned short* Wob = (unsigned short*)(ws + 14 * MB);  // Wo[o][d] already B^T layout
  unsigned short* Qb  = (unsigned short*)(ws + 16 * MB);  // [B*H][S][HD]
  unsigned short* Kb  = (unsigned short*)(ws + 24 * MB);  // [B*H][S][HD]
  unsigned short* VTb = (unsigned short*)(ws + 32 * MB);  // [B*H][HD][S]
  unsigned short* Cx  = (unsigned short*)(ws + 40 * MB);  // [B][S][D] bf16
  // attn partials reuse regions dead by attn time:
  unsigned short* pctx = (unsigned short*)(ws + 0 * MB);  // [512][128][64] bf16 = 8 MB (over xb)
  float*          pml  = (float*)(ws + 8 * MB);           // [512][128][2] f32 = 0.5 MB (over WT)

  cvt_kernel<<<(M_ * D_ / 4 + 255) / 256, 256, 0, stream>>>(x, xb, M_ * D_ / 4);
  cvt_kernel<<<(D_ * D_ / 4 + 255) / 256, 256, 0, stream>>>(Wo, Wob, D_ * D_ / 4);
  transpose_cvt3<<<dim3(32, 32, 3), dim3(32, 8), 0, stream>>>(Wq, Wk, Wv, WT);

  // fused QKV projection: N = 3072, Q pre-scaled by HD^-0.5 * log2(e)
  gemm_bt<<<dim3(3 * D_ / BN, M_ / BM), 256, 0, stream>>>(
      xb, WT, (void*)Qb, (void*)Kb, (void*)VTb, nullptr, 0, 0.18033688011112042f);

  // kv-split attention: 768 blocks (chain-descending), then 256-block merge
  attn_kernel<<<dim3(B_ * H_, 24), 256, 0, stream>>>(Qb, Kb, VTb, Cx, pctx, pml);
  merge_kernel<<<256, 256, 0, stream>>>(pctx, pml, Cx);

  gemm_bt<<<dim3(D_ / BN, M_ / BM), 256, 0, stream>>>(
      Cx, Wob, (void*)out, nullptr, nullptr, bo, 1, 1.0f);
}